// Round 2
// baseline (1343.382 us; speedup 1.0000x reference)
//
#include <hip/hip_runtime.h>
#include <math.h>

#define N_TOK 2048
#define BATCH 64
#define DIN   768
#define DMID  512
#define DOUT  128
#define TILE_N 64   // rows per block
#define KC    64    // k-chunk of x staged in LDS
#define MC    128   // D_MID chunk per pass (4 passes)

// Float atomic max via int/uint trick (order-preserving for IEEE-754).
__device__ __forceinline__ void atomicMaxFloat(float* addr, float val) {
    if (val >= 0.0f) atomicMax((int*)addr, __float_as_int(val));
    else             atomicMin((unsigned int*)addr, __float_as_uint(val));
}

__global__ void init_kernel(float* __restrict__ x1) {
    int i = blockIdx.x * blockDim.x + threadIdx.x;
    if (i < BATCH * DOUT) x1[i] = -INFINITY;
}

// One block = 64 rows of one sample b. Blocks not intersecting the segment exit.
// Thread map: 8 row-groups x 32 col-groups; per-thread 8 rows x 4 cols.
// D_MID processed in 4 chunks of 128 so hs is 32KB; GEMM2 acc lives in regs.
__global__ __launch_bounds__(256, 3) void fused_kernel(
    const float* __restrict__ x,   // (N, B, DIN)
    const float* __restrict__ W1,  // (DIN, DMID)
    const float* __restrict__ b1,  // (DMID)
    const float* __restrict__ W2,  // (DMID, DOUT)
    const float* __restrict__ b2,  // (DOUT)
    const int*   __restrict__ batch_list,
    float* __restrict__ x1)        // (B, DOUT), pre-set to -inf
{
    const int b    = blockIdx.y;
    const int row0 = blockIdx.x * TILE_N;

    const int start = (b == 0) ? 0 : batch_list[b - 1];
    const int len   = batch_list[b];
    const int end   = start + len;
    if (row0 >= end || row0 + TILE_N <= start) return;  // block-uniform exit

    __shared__ float xs[TILE_N][KC];   // 16 KB; reused as reduce buf at the end
    __shared__ float hs[TILE_N][MC];   // 32 KB

    const int tid = threadIdx.x;
    const int tr  = tid >> 5;   // 0..7  (row group: rows tr*8 .. +7)
    const int tc  = tid & 31;   // 0..31 (col group: cols tc*4 .. +3)

    float acc2[8][4];           // GEMM2 accumulators, persist across MC chunks
    #pragma unroll
    for (int r = 0; r < 8; ++r)
        #pragma unroll
        for (int c = 0; c < 4; ++c) acc2[r][c] = 0.0f;

    for (int mc = 0; mc < DMID; mc += MC) {
        // ---------------- GEMM1 chunk: hs[64][128] = relu(x_tile @ W1[:,mc:mc+128] + b1) ----
        float acc1[8][4];
        #pragma unroll
        for (int r = 0; r < 8; ++r)
            #pragma unroll
            for (int c = 0; c < 4; ++c) acc1[r][c] = 0.0f;

        const float* W1c = W1 + mc + tc * 4;

        for (int kc = 0; kc < DIN; kc += KC) {
            __syncthreads();  // previous chunk's xs reads (and prior-mc hs reads) done
            // stage x chunk: 64 rows x 64 k = 1024 float4, 4 per thread, coalesced
            #pragma unroll
            for (int j = 0; j < 4; ++j) {
                const int i  = tid + j * 256;
                const int r  = i >> 4;         // 0..63
                const int kq = i & 15;         // 0..15
                *(float4*)&xs[r][kq * 4] =
                    *(const float4*)&x[((size_t)(row0 + r) * BATCH + b) * DIN + kc + kq * 4];
            }
            __syncthreads();

            #pragma unroll 4
            for (int k = 0; k < KC; ++k) {
                const float4 w = *(const float4*)&W1c[(size_t)(kc + k) * DMID];
                float xv[8];
                #pragma unroll
                for (int r = 0; r < 8; ++r) xv[r] = xs[tr * 8 + r][k];
                #pragma unroll
                for (int r = 0; r < 8; ++r) {
                    acc1[r][0] = fmaf(xv[r], w.x, acc1[r][0]);
                    acc1[r][1] = fmaf(xv[r], w.y, acc1[r][1]);
                    acc1[r][2] = fmaf(xv[r], w.z, acc1[r][2]);
                    acc1[r][3] = fmaf(xv[r], w.w, acc1[r][3]);
                }
            }
        }

        // bias + relu -> hs
        {
            const float4 bb = *(const float4*)&b1[mc + tc * 4];
            const float bv[4] = {bb.x, bb.y, bb.z, bb.w};
            #pragma unroll
            for (int r = 0; r < 8; ++r) {
                float4 hv;
                hv.x = fmaxf(acc1[r][0] + bv[0], 0.0f);
                hv.y = fmaxf(acc1[r][1] + bv[1], 0.0f);
                hv.z = fmaxf(acc1[r][2] + bv[2], 0.0f);
                hv.w = fmaxf(acc1[r][3] + bv[3], 0.0f);
                *(float4*)&hs[tr * 8 + r][tc * 4] = hv;
            }
        }
        __syncthreads();

        // ---------------- GEMM2 partial: acc2 += hs @ W2[mc:mc+128, :] ----------------
        const float* W2c = W2 + (size_t)mc * DOUT + tc * 4;
        #pragma unroll 4
        for (int kk = 0; kk < MC; ++kk) {
            const float4 w = *(const float4*)&W2c[(size_t)kk * DOUT];
            float hv[8];
            #pragma unroll
            for (int r = 0; r < 8; ++r) hv[r] = hs[tr * 8 + r][kk];
            #pragma unroll
            for (int r = 0; r < 8; ++r) {
                acc2[r][0] = fmaf(hv[r], w.x, acc2[r][0]);
                acc2[r][1] = fmaf(hv[r], w.y, acc2[r][1]);
                acc2[r][2] = fmaf(hv[r], w.z, acc2[r][2]);
                acc2[r][3] = fmaf(hv[r], w.w, acc2[r][3]);
            }
        }
        // next mc iteration's first __syncthreads() guards the hs/xs overwrite
    }

    // ---------------- bias + segment mask + per-thread column max ----------------
    const float4 bb2 = *(const float4*)&b2[tc * 4];
    const float bv2[4] = {bb2.x, bb2.y, bb2.z, bb2.w};
    float cmax[4] = {-INFINITY, -INFINITY, -INFINITY, -INFINITY};
    #pragma unroll
    for (int r = 0; r < 8; ++r) {
        const int row = row0 + tr * 8 + r;
        const bool in = (row >= start) && (row < end);
        #pragma unroll
        for (int c = 0; c < 4; ++c) {
            const float v = acc2[r][c] + bv2[c];
            if (in) cmax[c] = fmaxf(cmax[c], v);
        }
    }

    // block reduce over the 8 row-groups (reuse xs as [8][DOUT]) -> atomic max
    float (*red)[DOUT] = (float(*)[DOUT])xs;
    #pragma unroll
    for (int c = 0; c < 4; ++c) red[tr][tc * 4 + c] = cmax[c];
    __syncthreads();

    if (tid < DOUT) {
        float m = red[0][tid];
        #pragma unroll
        for (int r = 1; r < 8; ++r) m = fmaxf(m, red[r][tid]);
        atomicMaxFloat(&x1[b * DOUT + tid], m);
    }
}

// argmax(softmax(x1)) == argmax(x1); first-index tie semantics match strict >.
__global__ void argmax_kernel(const float* __restrict__ x1, float* __restrict__ probs) {
    int b = blockIdx.x * blockDim.x + threadIdx.x;
    if (b >= BATCH) return;
    const float* row = x1 + b * DOUT;
    float best = row[0];
    int bi = 0;
    for (int c = 1; c < DOUT; ++c) {
        float v = row[c];
        if (v > best) { best = v; bi = c; }
    }
    probs[b] = (float)bi;
}

extern "C" void kernel_launch(void* const* d_in, const int* in_sizes, int n_in,
                              void* d_out, int out_size, void* d_ws, size_t ws_size,
                              hipStream_t stream) {
    const float* x          = (const float*)d_in[0];
    const float* W1         = (const float*)d_in[1];
    const float* b1         = (const float*)d_in[2];
    const float* W2         = (const float*)d_in[3];
    const float* b2         = (const float*)d_in[4];
    const int*   batch_list = (const int*)d_in[5];

    float* x1    = (float*)d_out;          // 64*128
    float* probs = x1 + BATCH * DOUT;      // 64

    init_kernel<<<(BATCH * DOUT + 255) / 256, 256, 0, stream>>>(x1);

    dim3 grid(N_TOK / TILE_N, BATCH);
    fused_kernel<<<grid, 256, 0, stream>>>(x, W1, b1, W2, b2, batch_list, x1);

    argmax_kernel<<<1, 64, 0, stream>>>(x1, probs);
}